// Round 1
// baseline (18563.942 us; speedup 1.0000x reference)
//
#include <hip/hip_runtime.h>
#include <math.h>

#define NN 10000
#define NE 160000
#define TSTEPS 64
#define FIN 16
#define HID 128
#define TC 8          // GCN timestep chunk
#define TMROW 40      // LSTM gemm row tile (10000 % 40 == 0)

// ---- workspace element offsets (floats/ints, all 4B) ----
#define OFF_DINV   0ul
#define OFF_DEG    16384ul
#define OFF_ROWPTR 32768ul
#define OFF_CURSOR 49152ul
#define OFF_CSRC   65536ul
#define OFF_CSRW   (OFF_CSRC + (size_t)NE)
#define OFF_WZT    (OFF_CSRW + (size_t)NE)
#define OFF_WHT    (OFF_WZT + 131072ul)
#define OFF_WCT    (OFF_WHT + 16384ul)
#define OFF_HBUF   (OFF_WCT + 16384ul)
#define OFF_CBUF   (OFF_HBUF + (size_t)NN*HID)
#define OFF_Z      (OFF_CBUF + (size_t)NN*HID)
#define OFF_BUFA   (OFF_Z + (size_t)NN*4*HID)
#define OFF_BUFB   (OFF_BUFA + (size_t)TC*NN*HID)

__device__ __forceinline__ float sigf(float x){ return 1.f/(1.f + expf(-x)); }

// ---- weight transposes: WzT[j*512+k] = [Wih;Whh][k][j], WhT/WcT [j*128+k] ----
__global__ void k_transpose(const float* __restrict__ Wih, const float* __restrict__ Whh,
                            const float* __restrict__ Wh,  const float* __restrict__ Wc,
                            float* __restrict__ WzT, float* __restrict__ WhT, float* __restrict__ WcT){
  int idx = blockIdx.x*blockDim.x + threadIdx.x;   // 0..65535
  int k = idx >> 7;        // 0..511
  int j = idx & 127;       // 0..127
  WzT[(size_t)j*512 + k]        = Wih[(size_t)k*HID + j];
  WzT[(size_t)(HID+j)*512 + k]  = Whh[(size_t)k*HID + j];
  if (k < HID){
    WhT[(size_t)j*HID + k] = Wh[(size_t)k*HID + j];
    WcT[(size_t)j*HID + k] = Wc[(size_t)k*HID + j];
  }
}

__global__ void k_degcount(const int* __restrict__ edges, int* __restrict__ degcnt){
  int e = blockIdx.x*blockDim.x + threadIdx.x;
  if (e < NE) atomicAdd(&degcnt[edges[NE + e]], 1);
}

__global__ void k_dinv(const int* __restrict__ degcnt, float* __restrict__ dinv){
  int n = blockIdx.x*blockDim.x + threadIdx.x;
  if (n < NN) dinv[n] = rsqrtf((float)(degcnt[n] + 1));   // +1 self loop, always >=1
}

// single-block scan: rowptr[0]=0, rowptr[n+1]=sum(degcnt[0..n])
__global__ void k_scan(const int* __restrict__ degcnt, int* __restrict__ rowptr){
  __shared__ int sd[1024];
  __shared__ int carry;
  if (threadIdx.x == 0){ carry = 0; rowptr[0] = 0; }
  __syncthreads();
  for (int base = 0; base < NN; base += 1024){
    int i = base + threadIdx.x;
    int v = (i < NN) ? degcnt[i] : 0;
    sd[threadIdx.x] = v;
    __syncthreads();
    for (int off = 1; off < 1024; off <<= 1){
      int t = (threadIdx.x >= off) ? sd[threadIdx.x - off] : 0;
      __syncthreads();
      sd[threadIdx.x] += t;
      __syncthreads();
    }
    int incl = sd[threadIdx.x] + carry;
    if (i < NN) rowptr[i+1] = incl;
    __syncthreads();
    if (threadIdx.x == 1023) carry = incl;
    __syncthreads();
  }
}

__global__ void k_csrfill(const int* __restrict__ edges, const int* __restrict__ rowptr,
                          int* __restrict__ cursor, int* __restrict__ csrc, float* __restrict__ csrw,
                          const float* __restrict__ dinv){
  int e = blockIdx.x*blockDim.x + threadIdx.x;
  if (e >= NE) return;
  int s = edges[e];
  int d = edges[NE + e];
  int pos = rowptr[d] + atomicAdd(&cursor[d], 1);
  csrc[pos] = s;
  csrw[pos] = dinv[s] * dinv[d];
}

// x_t @ W1 for a chunk of TC timesteps: bufA[tt][n][j]
__global__ void k_gemm1(const float* __restrict__ inputs, const float* __restrict__ W1,
                        float* __restrict__ out, int c0){
  int idx = blockIdx.x*256 + threadIdx.x;    // TC*NN*HID total
  int j  = idx & 127;
  int n  = (idx >> 7) % NN;
  int tt = idx / (NN*HID);
  int t  = c0 + tt;
  const float* x = inputs + (size_t)n*TSTEPS*FIN + (size_t)t*FIN;
  float acc = 0.f;
  #pragma unroll
  for (int f = 0; f < FIN; f++) acc += x[f] * W1[f*HID + j];
  out[(size_t)tt*NN*HID + (size_t)n*HID + j] = acc;
}

// CSR gather aggregate + self loop + bias + relu: bufB[tt][n][j]
__global__ void k_agg_relu(const float* __restrict__ hbuf, const int* __restrict__ rowptr,
                           const int* __restrict__ csrc, const float* __restrict__ csrw,
                           const float* __restrict__ dinv, const float* __restrict__ b1,
                           float* __restrict__ out){
  int n = blockIdx.x, tt = blockIdx.y, j = threadIdx.x;
  const float* hb = hbuf + (size_t)tt*NN*HID;
  float dn = dinv[n];
  float acc = hb[(size_t)n*HID + j] * (dn*dn);
  int beg = rowptr[n], end = rowptr[n+1];
  for (int k = beg; k < end; k++){
    int s = csrc[k]; float w = csrw[k];
    acc += hb[(size_t)s*HID + j] * w;
  }
  acc += b1[j];
  out[(size_t)tt*NN*HID + (size_t)n*HID + j] = fmaxf(acc, 0.f);
}

// [rows,128] @ W[128,128] (j-major, x@W orientation)
__global__ void k_gemm2(const float* __restrict__ X, const float* __restrict__ W,
                        float* __restrict__ out){
  int k = threadIdx.x;                       // 128
  size_t r0 = (size_t)blockIdx.x * 16;
  float acc[16];
  #pragma unroll
  for (int m = 0; m < 16; m++) acc[m] = 0.f;
  const float* xp = X + r0*HID;
  for (int j = 0; j < HID; j++){
    float w = W[j*HID + k];
    #pragma unroll
    for (int m = 0; m < 16; m++) acc[m] += xp[(size_t)m*HID + j] * w;
  }
  #pragma unroll
  for (int m = 0; m < 16; m++) out[(r0+m)*HID + k] = acc[m];
}

// aggregate layer-2 + b2, then LayerNorm(ln2); writes g into d_out series slot [n,t,:]
__global__ void k_agg_ln(const float* __restrict__ hbuf, const int* __restrict__ rowptr,
                         const int* __restrict__ csrc, const float* __restrict__ csrw,
                         const float* __restrict__ dinv, const float* __restrict__ b2,
                         const float* __restrict__ ln2g, const float* __restrict__ ln2b,
                         float* __restrict__ outg, int c0){
  __shared__ float sb[4];
  int n = blockIdx.x, tt = blockIdx.y, j = threadIdx.x;
  const float* hb = hbuf + (size_t)tt*NN*HID;
  float dn = dinv[n];
  float acc = hb[(size_t)n*HID + j] * (dn*dn);
  int beg = rowptr[n], end = rowptr[n+1];
  for (int k = beg; k < end; k++){
    int s = csrc[k]; float w = csrw[k];
    acc += hb[(size_t)s*HID + j] * w;
  }
  acc += b2[j];
  // LayerNorm over 128 lanes (2 waves)
  float s1 = acc, s2 = acc*acc;
  #pragma unroll
  for (int off = 32; off; off >>= 1){
    s1 += __shfl_down(s1, off, 64);
    s2 += __shfl_down(s2, off, 64);
  }
  if ((j & 63) == 0){ sb[j>>6] = s1; sb[(j>>6)+2] = s2; }
  __syncthreads();
  float sum = sb[0]+sb[1], sum2 = sb[2]+sb[3];
  float mean = sum * (1.f/128.f);
  float var  = sum2 * (1.f/128.f) - mean*mean;
  float rs   = rsqrtf(var + 1e-5f);
  int t = c0 + tt;
  outg[(size_t)n*TSTEPS*HID + (size_t)t*HID + j] = (acc - mean)*rs*ln2g[j] + ln2b[j];
}

// z[n,0:512] = bih+bhh + g[n,t,:]@Wih^T + h[n,:]@Whh^T
__global__ void k_lstm_gemm(const float* __restrict__ g, const float* __restrict__ h,
                            const float* __restrict__ WzT, const float* __restrict__ bih,
                            const float* __restrict__ bhh, float* __restrict__ z, int t){
  int k = threadIdx.x;                   // 0..511
  int n0 = blockIdx.x * TMROW;
  float bb = bih[k] + bhh[k];
  float acc[TMROW];
  #pragma unroll
  for (int m = 0; m < TMROW; m++) acc[m] = bb;
  const float* gp = g + (size_t)n0*TSTEPS*HID + (size_t)t*HID;
  for (int j = 0; j < HID; j++){
    float w = WzT[(size_t)j*512 + k];
    #pragma unroll
    for (int m = 0; m < TMROW; m++) acc[m] += gp[(size_t)m*TSTEPS*HID + j] * w;
  }
  const float* hp = h + (size_t)n0*HID;
  for (int j = 0; j < HID; j++){
    float w = WzT[(size_t)(HID+j)*512 + k];
    #pragma unroll
    for (int m = 0; m < TMROW; m++) acc[m] += hp[(size_t)m*HID + j] * w;
  }
  #pragma unroll
  for (int m = 0; m < TMROW; m++) z[(size_t)(n0+m)*512 + k] = acc[m];
}

// LSTM pointwise update + LayerNorm(ln1) + write series[n,t,:]
__global__ void k_lstm_point(const float* __restrict__ z, float* __restrict__ h, float* __restrict__ c,
                             const float* __restrict__ ln1g, const float* __restrict__ ln1b,
                             float* __restrict__ outS, int t){
  __shared__ float sb[4];
  int n = blockIdx.x, j = threadIdx.x;
  size_t zb = (size_t)n*512;
  float zi = z[zb + j], zf = z[zb + 128 + j], zg = z[zb + 256 + j], zo = z[zb + 384 + j];
  size_t hb = (size_t)n*HID + j;
  float cp = c[hb];
  float cn = sigf(zf)*cp + sigf(zi)*tanhf(zg);
  float hn = sigf(zo)*tanhf(cn);
  c[hb] = cn;
  h[hb] = hn;
  float s1 = hn, s2 = hn*hn;
  #pragma unroll
  for (int off = 32; off; off >>= 1){
    s1 += __shfl_down(s1, off, 64);
    s2 += __shfl_down(s2, off, 64);
  }
  if ((j & 63) == 0){ sb[j>>6] = s1; sb[(j>>6)+2] = s2; }
  __syncthreads();
  float sum = sb[0]+sb[1], sum2 = sb[2]+sb[3];
  float mean = sum * (1.f/128.f);
  float var  = sum2 * (1.f/128.f) - mean*mean;
  float rs   = rsqrtf(var + 1e-5f);
  outS[(size_t)n*TSTEPS*HID + (size_t)t*HID + j] = (hn - mean)*rs*ln1g[j] + ln1b[j];
}

// out[n,k] = act(b[k] + X[n,:]@WT[:,k]); WT is [128,128] j-major
__global__ void k_final_gemm(const float* __restrict__ X, const float* __restrict__ WT,
                             const float* __restrict__ b, float* __restrict__ out, int do_tanh){
  int k = threadIdx.x;
  size_t n0 = (size_t)blockIdx.x * 16;
  float acc[16];
  float bb = b[k];
  #pragma unroll
  for (int m = 0; m < 16; m++) acc[m] = bb;
  const float* xp = X + n0*HID;
  for (int j = 0; j < HID; j++){
    float w = WT[j*HID + k];
    #pragma unroll
    for (int m = 0; m < 16; m++) acc[m] += xp[(size_t)m*HID + j] * w;
  }
  #pragma unroll
  for (int m = 0; m < 16; m++){
    float v = acc[m];
    if (do_tanh) v = tanhf(v);
    out[(n0+m)*HID + k] = v;
  }
}

extern "C" void kernel_launch(void* const* d_in, const int* in_sizes, int n_in,
                              void* d_out, int out_size, void* d_ws, size_t ws_size,
                              hipStream_t stream){
  const float* inputs = (const float*)d_in[0];
  const int*   edges  = (const int*)  d_in[1];
  const float* W1  = (const float*)d_in[2];
  const float* b1  = (const float*)d_in[3];
  const float* W2  = (const float*)d_in[4];
  const float* b2  = (const float*)d_in[5];
  const float* Wih = (const float*)d_in[6];
  const float* Whh = (const float*)d_in[7];
  const float* bih = (const float*)d_in[8];
  const float* bhh = (const float*)d_in[9];
  const float* ln1g = (const float*)d_in[10];
  const float* ln1b = (const float*)d_in[11];
  const float* ln2g = (const float*)d_in[12];
  const float* ln2b = (const float*)d_in[13];
  const float* Wh  = (const float*)d_in[14];
  const float* bh  = (const float*)d_in[15];
  const float* Wc  = (const float*)d_in[16];
  const float* bc  = (const float*)d_in[17];

  float* out = (float*)d_out;
  float* ws  = (float*)d_ws;

  float* dinv   = ws + OFF_DINV;
  int*   degcnt = (int*)(ws + OFF_DEG);
  int*   rowptr = (int*)(ws + OFF_ROWPTR);
  int*   cursor = (int*)(ws + OFF_CURSOR);
  int*   csrc   = (int*)(ws + OFF_CSRC);
  float* csrw   = ws + OFF_CSRW;
  float* WzT    = ws + OFF_WZT;
  float* WhT    = ws + OFF_WHT;
  float* WcT    = ws + OFF_WCT;
  float* hbuf   = ws + OFF_HBUF;
  float* cbuf   = ws + OFF_CBUF;
  float* zbuf   = ws + OFF_Z;
  float* bufA   = ws + OFF_BUFA;
  float* bufB   = ws + OFF_BUFB;

  hipMemsetAsync(degcnt, 0, NN*sizeof(int), stream);
  hipMemsetAsync(cursor, 0, NN*sizeof(int), stream);
  hipMemsetAsync(hbuf,   0, (size_t)2*NN*HID*sizeof(float), stream);  // h and c contiguous

  k_transpose<<<256, 256, 0, stream>>>(Wih, Whh, Wh, Wc, WzT, WhT, WcT);
  k_degcount<<<(NE+255)/256, 256, 0, stream>>>(edges, degcnt);
  k_dinv<<<(NN+255)/256, 256, 0, stream>>>(degcnt, dinv);
  k_scan<<<1, 1024, 0, stream>>>(degcnt, rowptr);
  k_csrfill<<<(NE+255)/256, 256, 0, stream>>>(edges, rowptr, cursor, csrc, csrw, dinv);

  // ---- GCN, chunked over timesteps; g (post-LN2) written into d_out series region ----
  for (int c0 = 0; c0 < TSTEPS; c0 += TC){
    k_gemm1<<<(TC*NN*HID)/256, 256, 0, stream>>>(inputs, W1, bufA, c0);
    k_agg_relu<<<dim3(NN, TC), 128, 0, stream>>>(bufA, rowptr, csrc, csrw, dinv, b1, bufB);
    k_gemm2<<<(TC*NN)/16, 128, 0, stream>>>(bufB, W2, bufA);
    k_agg_ln<<<dim3(NN, TC), 128, 0, stream>>>(bufA, rowptr, csrc, csrw, dinv, b2, ln2g, ln2b, out, c0);
  }

  // ---- LSTM over time; reads g slot t from d_out, overwrites with final series ----
  for (int t = 0; t < TSTEPS; t++){
    k_lstm_gemm<<<NN/TMROW, 512, 0, stream>>>(out, hbuf, WzT, bih, bhh, zbuf, t);
    k_lstm_point<<<NN, 128, 0, stream>>>(zbuf, hbuf, cbuf, ln1g, ln1b, out, t);
  }

  // ---- final projections ----
  float* outHidden = out + (size_t)NN*TSTEPS*HID;
  float* outCell   = outHidden + (size_t)NN*HID;
  k_final_gemm<<<NN/16, 128, 0, stream>>>(hbuf, WhT, bh, outHidden, 1);
  k_final_gemm<<<NN/16, 128, 0, stream>>>(cbuf, WcT, bc, outCell, 0);
}